// Round 9
// baseline (5506.763 us; speedup 1.0000x reference)
//
#include <hip/hip_runtime.h>
#include <cstdint>
#include <cstddef>

// Problem constants
#define Bb   128
#define Tt   500
#define INn  306
#define Hh   512
#define GRID 128
#define BH32 (Bb * Hh)              // 65536 u32 per plane-slot (packed hi|lo)

typedef short bf16x8 __attribute__((ext_vector_type(8)));
typedef float f32x4  __attribute__((ext_vector_type(4)));
typedef unsigned u32x4 __attribute__((ext_vector_type(4)));
typedef unsigned short u16t;

union F8 { bf16x8 v; uint4 q; unsigned u[4]; u16t s[8]; };

__device__ __forceinline__ float bf2f(u16t h) {
  unsigned u = ((unsigned)h) << 16;
  return __builtin_bit_cast(float, u);
}
__device__ __forceinline__ u16t f2bf(float f) {
  unsigned u = __builtin_bit_cast(unsigned, f);
  unsigned r = u + 0x7fffu + ((u >> 16) & 1u);   // RNE (finite inputs only)
  return (u16t)(r >> 16);
}
__device__ __forceinline__ void splitRNE(float v, u16t& hi, u16t& lo) {
  hi = f2bf(v);
  lo = f2bf(v - bf2f(hi));
}
__device__ __forceinline__ void splitTR(float v, u16t& hi, u16t& lo) {
  unsigned u = __builtin_bit_cast(unsigned, v);
  hi = (u16t)(u >> 16);
  float hf = __builtin_bit_cast(float, u & 0xFFFF0000u);
  lo = (u16t)(__builtin_bit_cast(unsigned, v - hf) >> 16);
}
__device__ __forceinline__ f32x4 MF(const F8& a, const F8& b, f32x4 c) {
  return __builtin_amdgcn_mfma_f32_16x16x32_bf16(a.v, b.v, c, 0, 0, 0);
}

// Agent-scope (sc1) primitives: used by SAFE path + one-time verdict.
__device__ __forceinline__ void stw(unsigned* p, unsigned v) {
  __hip_atomic_store(p, v, __ATOMIC_RELAXED, __HIP_MEMORY_SCOPE_AGENT);
}
__device__ __forceinline__ unsigned ldw(const unsigned* p) {
  return __hip_atomic_load(p, __ATOMIC_RELAXED, __HIP_MEMORY_SCOPE_AGENT);
}

// ---------------------------------------------------------------------------
// MERGED-LAYER protocol (round-8 design, resubmitted verbatim after an
// infra-pattern container failure; protocol re-audited, no fault found):
//   Waves 0-1: layer 0 for cols [sub*32, sub*32+32)
//   Waves 2-3: layer 1 for the same cols
// Iter t (t=0..500): compute h0[t] (L0 waves, t<500) and h1[t-1] (L1 waves,
// t>=1). ONE flag per WG per round certifies both publishes -> the critical
// cycle has ONE drain + ONE flag-visibility hop per round (round 7 had two
// of each; measured 10.26 us/round).
// Gates: iter t (t>=1) needs ALL 16 subs' flag(t-1)==t. Flag(t-1) stored at
// iter t phase B (after per-wave vmcnt(0) drain + barrier -> release).
// Ring safety: h0 slot t&1 overwrites h0[t-2], staged by peers at iter t-1
//   phase D; gate(t) => peers stored flag(t-1) => finished iter t-1.
//   h1 slot (t-1)&1 overwrites h1[t-3], staged at iter t-1 phase D (same
//   transitive argument). Flag slot (t-1)&1 stamp t overwrites stamp t-2;
//   writer passed gate(t-1) => peers past iter t-1 phase B => peers past
//   their gate(t-2) poll. Deadlock-free: flag store precedes gate per iter.
// FAST/SAFE selection identical to round 7 (proven): unanimous XCC_ID =>
// plain write-through stores + buffer_inv(L1)+plain loads; else sc1 path.
// Footprint: 1024 B flags + 1.00 MiB h (byte-identical to proven baseline).
// ---------------------------------------------------------------------------

template<bool FAST>
__device__ __forceinline__ void stf(unsigned* p, unsigned v) {
  if constexpr (FAST) *(volatile unsigned*)p = v;   // write-through L1 -> L2
  else stw(p, v);
}
template<bool FAST>
__device__ __forceinline__ void invL() {
  if constexpr (FAST) asm volatile("buffer_inv" ::: "memory");      // L1 only
  else asm volatile("buffer_inv sc1" ::: "memory");                 // L1+L2
}
template<bool FAST>
__device__ __forceinline__ void fpoll(const unsigned* p, unsigned v) {
  if constexpr (FAST) {
    for (;;) {
      asm volatile("buffer_inv" ::: "memory");      // drop stale L1 line
      if (*(const volatile unsigned*)p == v) break;
      __builtin_amdgcn_s_sleep(1);
    }
  } else {
    while (ldw(p) != v) __builtin_amdgcn_s_sleep(1);
  }
}

// Stage one packed 16x512 tile into hi/lo u16 LDS planes (16 KiB each).
// LDS layout: row-major [16][1024 B], 16B chunks swizzled c ^= (row&7).
__device__ __forceinline__ void stage_tile(const unsigned* __restrict__ gsrc,
                                           unsigned char* smHi,
                                           unsigned char* smLo, int tid) {
  const int row = tid >> 4;            // 0..15
  const int c0  = tid & 15;
#pragma unroll
  for (int k = 0; k < 8; ++k) {
    const int cg = c0 + k * 16;        // 16B packed chunk (4 cols)
    const u32x4 w = *(const u32x4*)(gsrc + (size_t)row * Hh + (size_t)cg * 4);
    const unsigned hi0 = (w[1] & 0xFFFF0000u) | (w[0] >> 16);
    const unsigned hi1 = (w[3] & 0xFFFF0000u) | (w[2] >> 16);
    const unsigned lo0 = (w[1] << 16) | (w[0] & 0xFFFFu);
    const unsigned lo1 = (w[3] << 16) | (w[2] & 0xFFFFu);
    const int ch   = cg >> 1;          // 16B chunk in the u16 plane
    const int half = cg & 1;
    const size_t boff = (size_t)row * 1024 + ((size_t)(ch ^ (row & 7)) << 4)
                      + (size_t)half * 8;
    *(uint2*)(smHi + boff) = make_uint2(hi0, hi1);
    *(uint2*)(smLo + boff) = make_uint2(lo0, lo1);
  }
}
// Read one A-fragment (8 cols) for (row, kc, quad) from a staged plane.
__device__ __forceinline__ F8 fragLDS(const unsigned char* smP, int row,
                                      int kc, int quad) {
  const int c = kc * 4 + quad;
  F8 f;
  f.q = *(const uint4*)(smP + (size_t)row * 1024
                        + ((size_t)(c ^ (row & 7)) << 4));
  return f;
}

template<bool FAST>
__device__ void body(
    const float* x,
    const float* Wih0, const float* Whh0, const float* bih0, const float* bhh0,
    const float* Wih1, const float* Whh1, const float* bih1, const float* bhh1,
    const float* Wfc,  const float* bfc, float* out,
    unsigned* fl, unsigned* h0p, unsigned* h1p, unsigned char* sm,
    int sub, int tid, int Mb)
{
  const int lane = tid & 63;
  const int wave = tid >> 6;
  const int l15  = lane & 15;
  const int quad = lane >> 4;
  const bool isL0 = (wave < 2);

  unsigned char* smA = sm;             // h0[t-1] hi
  unsigned char* smB = sm + 16384;     // h0[t-1] lo
  unsigned char* smC = sm + 32768;     // h1[t-2] hi
  unsigned char* smD = sm + 49152;     // h1[t-2] lo

  const int jn    = sub * 32 + (wave & 1) * 16 + l15;  // col this lane owns
  const int mOutB = Mb + quad * 4;                     // C/D row = quad*4+r

  // ---- role-union weight registers: a thread is L0 xor L1 for the kernel.
  // L0: W[0..9]=Wih0 hi, W[10..19]=Wih0 lo, W[20..35]=Whh0 hi, W[36..51]=lo.
  // L1: W[0..15]=Wih1 hi, W[16..31]=lo, W[32..47]=Whh1 hi, W[48..63]=lo.
  F8 W[64];
  float bv;
  if (isL0) {
#pragma unroll
    for (int kc = 0; kc < 10; ++kc) {
#pragma unroll
      for (int e = 0; e < 8; ++e) {
        const int k = kc * 32 + quad * 8 + e;
        float v = (k < INn) ? Wih0[(size_t)jn * INn + k] : 0.f;
        splitRNE(v, W[kc].s[e], W[10 + kc].s[e]);
      }
    }
#pragma unroll
    for (int kc = 0; kc < 16; ++kc) {
      const float* wr = Whh0 + (size_t)jn * Hh + kc * 32 + quad * 8;
#pragma unroll
      for (int e = 0; e < 8; ++e)
        splitRNE(wr[e], W[20 + kc].s[e], W[36 + kc].s[e]);
    }
    bv = bih0[jn] + bhh0[jn];
  } else {
#pragma unroll
    for (int kc = 0; kc < 16; ++kc) {
      const float* w1 = Wih1 + (size_t)jn * Hh + kc * 32 + quad * 8;
      const float* w2 = Whh1 + (size_t)jn * Hh + kc * 32 + quad * 8;
#pragma unroll
      for (int e = 0; e < 8; ++e) {
        splitRNE(w1[e], W[kc].s[e], W[16 + kc].s[e]);
        splitRNE(w2[e], W[32 + kc].s[e], W[48 + kc].s[e]);
      }
    }
    bv = bih1[jn] + bhh1[jn];
  }

  const int rowA = Mb + l15;

  for (int t = 0; t <= Tt; ++t) {
    // ---- A: x[t] prep (L0 waves, t<500). Overlaps round t-1's store drain.
    F8 xh[10], xl[10];
    if (isL0 && t < Tt) {
      const float* xr = x + ((size_t)rowA * Tt + t) * INn;  // 8B-aligned
#pragma unroll
      for (int kc = 0; kc < 10; ++kc) {
        const int kb = kc * 32 + quad * 8;
        float v[8];
        if (kc < 9) {
          const float2* p = (const float2*)(xr + kb);
#pragma unroll
          for (int h2 = 0; h2 < 4; ++h2) {
            float2 w = p[h2];
            v[2 * h2] = w.x; v[2 * h2 + 1] = w.y;
          }
        } else {
#pragma unroll
          for (int e = 0; e < 8; ++e)
            v[e] = (kb + e < INn) ? xr[kb + e] : 0.f;
        }
#pragma unroll
        for (int e = 0; e < 8; ++e) splitTR(v[e], xh[kc].s[e], xl[kc].s[e]);
      }
    }

    // ---- B: release round t-1 (each wave drains its own stores, then the
    //         barrier orders all waves' drains before the flag store).
    asm volatile("s_waitcnt vmcnt(0)" ::: "memory");
    __syncthreads();
    if (t >= 1 && tid == 0)
      stf<FAST>(fl + sub * 2 + ((t - 1) & 1), (unsigned)t);

    // ---- C: gate on all 16 peers' flag(t-1) (skip own slot).
    if (t >= 1 && tid < 16 && tid != sub)
      fpoll<FAST>(fl + tid * 2 + ((t - 1) & 1), (unsigned)t);
    __syncthreads();
    invL<FAST>();                                  // acquire

    // ---- D: cooperative stage (all 256 threads).
    if (t >= 1)
      stage_tile(h0p + (size_t)((t - 1) & 1) * BH32 + (size_t)Mb * Hh,
                 smA, smB, tid);
    if (t >= 2)
      stage_tile(h1p + (size_t)((t - 2) & 1) * BH32 + (size_t)Mb * Hh,
                 smC, smD, tid);
    __syncthreads();

    // ---- E: compute + publish.
    if (isL0) {
      if (t < Tt) {
        f32x4 ac0 = {bv, bv, bv, bv};
        f32x4 ac1 = {0.f, 0.f, 0.f, 0.f};
        f32x4 ac2 = {0.f, 0.f, 0.f, 0.f};
        if (t >= 1) {
#pragma unroll
          for (int kc = 0; kc < 16; ++kc) {
            F8 ah = fragLDS(smA, l15, kc, quad);
            F8 al = fragLDS(smB, l15, kc, quad);
            ac0 = MF(ah, W[20 + kc], ac0);
            ac1 = MF(ah, W[36 + kc], ac1);
            ac2 = MF(al, W[20 + kc], ac2);
          }
        }
#pragma unroll
        for (int kc = 0; kc < 10; ++kc) {
          ac0 = MF(xh[kc], W[kc], ac0);
          ac1 = MF(xh[kc], W[10 + kc], ac1);
          ac2 = MF(xl[kc], W[kc], ac2);
        }
        unsigned* dst = h0p + (size_t)(t & 1) * BH32;
#pragma unroll
        for (int r = 0; r < 4; ++r) {
          const float v = tanhf(ac0[r] + ac1[r] + ac2[r]);
          u16t hb, lb; splitRNE(v, hb, lb);
          stf<FAST>(dst + (size_t)(mOutB + r) * Hh + jn,
                    ((unsigned)hb << 16) | (unsigned)lb);
        }
      }
    } else {
      if (t >= 1) {
        f32x4 ac0 = {bv, bv, bv, bv};
        f32x4 ac1 = {0.f, 0.f, 0.f, 0.f};
        f32x4 ac2 = {0.f, 0.f, 0.f, 0.f};
#pragma unroll
        for (int kc = 0; kc < 16; ++kc) {
          F8 ah = fragLDS(smA, l15, kc, quad);
          F8 al = fragLDS(smB, l15, kc, quad);
          ac0 = MF(ah, W[kc], ac0);
          ac1 = MF(ah, W[16 + kc], ac1);
          ac2 = MF(al, W[kc], ac2);
        }
        if (t >= 2) {
#pragma unroll
          for (int kc = 0; kc < 16; ++kc) {
            F8 ah = fragLDS(smC, l15, kc, quad);
            F8 al = fragLDS(smD, l15, kc, quad);
            ac0 = MF(ah, W[32 + kc], ac0);
            ac1 = MF(ah, W[48 + kc], ac1);
            ac2 = MF(al, W[32 + kc], ac2);
          }
        }
        unsigned* dst = h1p + (size_t)((t - 1) & 1) * BH32;
#pragma unroll
        for (int r = 0; r < 4; ++r) {
          const float v = tanhf(ac0[r] + ac1[r] + ac2[r]);
          u16t hb, lb; splitRNE(v, hb, lb);
          stf<FAST>(dst + (size_t)(mOutB + r) * Hh + jn,
                    ((unsigned)hb << 16) | (unsigned)lb);
        }
      }
    }
  }

  // ---- Epilogue: final release (flag(500) stamp 501, slot 0 — ring-safe:
  // writer passed gate(500), so every peer finished its gate(498) poll of
  // the stamp being overwritten).
  asm volatile("s_waitcnt vmcnt(0)" ::: "memory");
  __syncthreads();
  if (tid == 0) stf<FAST>(fl + sub * 2 + (Tt & 1), (unsigned)(Tt + 1));

  // ---- FC + softmax for this group's 16 batch rows (sub==0 only).
  if (sub == 0) {
    if (tid < 16 && tid != 0)
      fpoll<FAST>(fl + tid * 2 + (Tt & 1), (unsigned)(Tt + 1));
    __syncthreads();
    invL<FAST>();
    if (tid < 16) {
      const int b = Mb + tid;
      const unsigned* hp = h1p + (size_t)((Tt - 1) & 1) * BH32
                         + (size_t)b * Hh;
      float acc[4] = {bfc[0], bfc[1], bfc[2], bfc[3]};
      for (int j = 0; j < Hh; ++j) {
        const unsigned w = *(const volatile unsigned*)(hp + j);
        const float hv = bf2f((u16t)(w >> 16)) + bf2f((u16t)(w & 0xFFFFu));
#pragma unroll
        for (int cc = 0; cc < 4; ++cc) acc[cc] += hv * Wfc[cc * Hh + j];
      }
      const float mx = fmaxf(fmaxf(acc[0], acc[1]), fmaxf(acc[2], acc[3]));
      const float e0 = expf(acc[0] - mx), e1 = expf(acc[1] - mx);
      const float e2 = expf(acc[2] - mx), e3 = expf(acc[3] - mx);
      const float si = 1.f / (e0 + e1 + e2 + e3);
      out[b * 4 + 0] = e0 * si;
      out[b * 4 + 1] = e1 * si;
      out[b * 4 + 2] = e2 * si;
      out[b * 4 + 3] = e3 * si;
    }
  }
}

__global__ __launch_bounds__(256, 1) void rnn_all(
    const float* x,
    const float* Wih0, const float* Whh0, const float* bih0, const float* bhh0,
    const float* Wih1, const float* Whh1, const float* bih1, const float* bhh1,
    const float* Wfc,  const float* bfc,
    float* out, unsigned char* ws)
{
  const int wg  = blockIdx.x;
  const int g   = wg & 7;     // group = wg%8: one XCD per group IF round-robin
  const int sub = wg >> 3;    // 0..15 = 32-col slice (both layers)
  const int tid = threadIdx.x;

  __shared__ __align__(16) unsigned char sm[65536];

  unsigned* fl  = (unsigned*)(ws + (size_t)g * 128);
  unsigned* h0p = (unsigned*)(ws + 1024);          // [2][128][512] packed u32
  unsigned* h1p = h0p + (size_t)2 * BH32;          // [2][128][512]
  const int Mb  = g * 16;

  // ---- One-time XCD co-residency verdict (identical to round 7, proven).
  // Table = h1 slot1 row Mb cols 0..15: first overwritten by h1[1] publishes
  // at iter 2, transitively gated on every WG finishing this phase.
  unsigned xcc;
  asm("s_getreg_b32 %0, hwreg(HW_REG_XCC_ID)" : "=s"(xcc));
  xcc &= 7u;
  unsigned* xt = h1p + (size_t)1 * BH32 + (size_t)Mb * Hh;
  if (tid == 0) stw(xt + sub, 0xA5C30000u | xcc);
  unsigned* xsh = (unsigned*)sm;                   // reuse staging LDS
  if (tid < 16) {
    unsigned v;
    do { v = ldw(xt + tid); } while ((v & 0xFFFFFFF8u) != 0xA5C30000u);
    xsh[tid] = v & 7u;
  }
  __syncthreads();
  bool fast = true;
  for (int i = 0; i < 16; ++i) fast = fast && (xsh[i] == xcc);
  __syncthreads();   // xsh dead; sm reused as staging below

  if (fast)
    body<true >(x, Wih0, Whh0, bih0, bhh0, Wih1, Whh1, bih1, bhh1,
                Wfc, bfc, out, fl, h0p, h1p, sm, sub, tid, Mb);
  else
    body<false>(x, Wih0, Whh0, bih0, bhh0, Wih1, Whh1, bih1, bhh1,
                Wfc, bfc, out, fl, h0p, h1p, sm, sub, tid, Mb);
}

extern "C" void kernel_launch(void* const* d_in, const int* in_sizes, int n_in,
                              void* d_out, int out_size, void* d_ws, size_t ws_size,
                              hipStream_t stream) {
  const float* x    = (const float*)d_in[0];
  const float* Wih0 = (const float*)d_in[1];
  const float* Whh0 = (const float*)d_in[2];
  const float* bih0 = (const float*)d_in[3];
  const float* bhh0 = (const float*)d_in[4];
  const float* Wih1 = (const float*)d_in[5];
  const float* Whh1 = (const float*)d_in[6];
  const float* bih1 = (const float*)d_in[7];
  const float* bhh1 = (const float*)d_in[8];
  const float* Wfc  = (const float*)d_in[9];
  const float* bfc  = (const float*)d_in[10];
  float* out = (float*)d_out;
  unsigned char* ws = (unsigned char*)d_ws;

  rnn_all<<<dim3(GRID), dim3(256), 0, stream>>>(
      x, Wih0, Whh0, bih0, bhh0, Wih1, Whh1, bih1, bhh1, Wfc, bfc, out, ws);
}